// Round 14
// baseline (146.290 us; speedup 1.0000x reference)
//
#include <hip/hip_runtime.h>
#include <hip/hip_bf16.h>

typedef __attribute__((ext_vector_type(8))) short short8;
typedef __attribute__((ext_vector_type(4))) float floatx4;

#define L2E 1.4426950408889634f

#if __has_builtin(__builtin_amdgcn_exp2f)
#define EXP2(x) __builtin_amdgcn_exp2f(x)
#else
#define EXP2(x) exp2f(x)
#endif
#if __has_builtin(__builtin_amdgcn_rcpf)
#define RCP(x) __builtin_amdgcn_rcpf(x)
#else
#define RCP(x) (1.0f / (x))
#endif

static __device__ __forceinline__ unsigned short f2bf(float f) {
    unsigned int u = __builtin_bit_cast(unsigned int, f);
    u += 0x7fffu + ((u >> 16) & 1u);   // RNE
    return (unsigned short)(u >> 16);
}
static __device__ __forceinline__ unsigned int pk_bf16(float a, float b) {
    __hip_bfloat162 h2 = __float22bfloat162_rn(make_float2(a, b));   // v_cvt_pk_bf16_f32
    unsigned int u;
    __builtin_memcpy(&u, &h2, 4);     // low16 = a, high16 = b
    return u;
}

// ---------------- 1) QKV GEMM (R25 verbatim: vectorized staging, LDS-bounced V^T) ----------------
__global__ __launch_bounds__(256) void k_qkv(const float* __restrict__ x,
                                             const float* __restrict__ qw,
                                             unsigned short* __restrict__ qm,
                                             unsigned short* __restrict__ km,
                                             unsigned short* __restrict__ vt) {
    __shared__ __align__(16) unsigned short At[64][136];
    __shared__ __align__(16) unsigned short Wt[64][136];
    const int tid = threadIdx.x;
    const int wave = tid >> 6, lane = tid & 63;
    const int l16 = lane & 15, quad = lane >> 4;
    const int m0 = blockIdx.x * 64;
    const int o0 = blockIdx.y * 64;

    floatx4 acc[4] = {};
    for (int rnd = 0; rnd < 2; ++rnd) {
        const int cbase = rnd * 128;
        if (rnd) __syncthreads();
        {
            const int tok0 = (tid & 15) * 4;
            const int c0   = (tid >> 4) * 8;
            const float* xp = x + (size_t)(cbase + c0) * 4096 + m0 + tok0;
            float4 v[8];
            #pragma unroll
            for (int j = 0; j < 8; ++j)
                v[j] = *reinterpret_cast<const float4*>(xp + (size_t)j * 4096);
            #pragma unroll
            for (int t = 0; t < 4; ++t) {
                unsigned int d[4];
                d[0] = pk_bf16((&v[0].x)[t], (&v[1].x)[t]);
                d[1] = pk_bf16((&v[2].x)[t], (&v[3].x)[t]);
                d[2] = pk_bf16((&v[4].x)[t], (&v[5].x)[t]);
                d[3] = pk_bf16((&v[6].x)[t], (&v[7].x)[t]);
                __builtin_memcpy(&At[tok0 + t][c0], d, 16);
            }
        }
        {
            const int o_l = tid >> 2, cp = (tid & 3) * 32;
            const float4* wp = reinterpret_cast<const float4*>(
                qw + (size_t)(o0 + o_l) * 256 + cbase + cp);
            #pragma unroll
            for (int j = 0; j < 2; ++j) {
                const float4 g0 = wp[4 * j + 0], g1 = wp[4 * j + 1];
                const float4 g2 = wp[4 * j + 2], g3 = wp[4 * j + 3];
                unsigned int u[8];
                u[0] = pk_bf16(g0.x, g0.y); u[1] = pk_bf16(g0.z, g0.w);
                u[2] = pk_bf16(g1.x, g1.y); u[3] = pk_bf16(g1.z, g1.w);
                u[4] = pk_bf16(g2.x, g2.y); u[5] = pk_bf16(g2.z, g2.w);
                u[6] = pk_bf16(g3.x, g3.y); u[7] = pk_bf16(g3.z, g3.w);
                __builtin_memcpy(&Wt[o_l][cp + 16 * j], u, 32);
            }
        }
        __syncthreads();
        #pragma unroll
        for (int cc = 0; cc < 4; ++cc) {
            const int c0 = cc * 32 + quad * 8;
            const short8 a = *reinterpret_cast<const short8*>(&At[wave * 16 + l16][c0]);
            #pragma unroll
            for (int t4 = 0; t4 < 4; ++t4) {
                const short8 b = *reinterpret_cast<const short8*>(&Wt[t4 * 16 + l16][c0]);
                acc[t4] = __builtin_amdgcn_mfma_f32_16x16x32_bf16(a, b, acc[t4], 0, 0, 0);
            }
        }
    }

    const int s = o0 >> 8;   // block-uniform: 0=q, 1=k, 2=v
    if (s < 2) {
        const float qscale = 0.17677669529663687f * L2E;
        #pragma unroll
        for (int t4 = 0; t4 < 4; ++t4) {
            #pragma unroll
            for (int r = 0; r < 4; ++r) {
                const int n = m0 + wave * 16 + quad * 4 + r;
                const int o = o0 + t4 * 16 + l16;
                const int rem = o & 255, head = rem >> 5, t = rem & 31;
                if (s == 0)  qm[((size_t)head * 4096 + n) * 32 + t] = f2bf(acc[t4][r] * qscale);
                else         km[((size_t)head * 4096 + n) * 32 + t] = f2bf(acc[t4][r]);
            }
        }
    } else {
        __syncthreads();
        unsigned short (*Ct)[72] = reinterpret_cast<unsigned short(*)[72]>(&At[0][0]);
        #pragma unroll
        for (int t4 = 0; t4 < 4; ++t4) {
            unsigned int d2[2];
            d2[0] = pk_bf16(acc[t4][0], acc[t4][1]);
            d2[1] = pk_bf16(acc[t4][2], acc[t4][3]);
            __builtin_memcpy(&Ct[t4 * 16 + l16][wave * 16 + quad * 4], d2, 8);
        }
        __syncthreads();
        const int row = tid >> 2, col0 = (tid & 3) * 16;
        unsigned short* dst = vt + (size_t)(o0 - 512 + row) * 4096 + m0 + col0;
        const short8 ca = *reinterpret_cast<const short8*>(&Ct[row][col0]);
        const short8 cb = *reinterpret_cast<const short8*>(&Ct[row][col0 + 8]);
        *reinterpret_cast<short8*>(dst) = ca;
        *reinterpret_cast<short8*>(dst + 8) = cb;
    }
}

// ---------------- 2) flash attention: 2 branch-free chains/phase, V direct-from-global ----------------
// R29: R28 (2 chains/phase) confirmed the chain-interleave theory (74.4->61.0us,
// MfmaUtil 9%, VALUBusy 38%). New accounting shows the LDS PIPE is now ~57%
// occupied per phase (~32 DS ops/wave/phase x 4 waves x 2 blocks vs 128B/cy/CU)
// -- the dominant busy resource. This round deletes V from LDS entirely: V
// fragments come DIRECTLY from global (R15-verified vt0/vt1+j0{+32} pattern).
// vt is L2/L3-resident (HBM 4%); loads issue at phase top with two SSTAGEs
// (~1000cy) as latency runway; loop is branch-free so nothing blocks hoisting.
// DS ops/wave/phase ~32 -> ~22 (-31%); V bank conflicts gone; LDS 50 -> 34KB.
// Cost: 4x V L2 traffic (~13us of L2 capacity over the dispatch) + ~16 VGPR.
__global__ __launch_bounds__(256, 2) void k_attn(const unsigned short* __restrict__ qm,
                                                 const unsigned short* __restrict__ km,
                                                 const unsigned short* __restrict__ vt,
                                                 unsigned short* __restrict__ ao) {
    const int h   = blockIdx.y;
    const int nq0 = blockIdx.x * 64;          // 64 q-rows per block (same dq for all)
    const int tid = threadIdx.x;
    const int wv  = tid >> 6;                 // wave owns q-tile nq0 + wv*16
    const int lane = tid & 63;
    const int l16 = lane & 15, quad = lane >> 4;
    const int nqw = nq0 + wv * 16;

    __shared__ __align__(16) unsigned short Kt[2][2][2048];   // [buf][slot][key*32+dim ^ swz]
    __shared__ __align__(16) unsigned short PT[4][2][16][72]; // [wave][slot][q][key] plain

    const short8 a_q = *reinterpret_cast<const short8*>(
        qm + ((size_t)h * 4096 + nqw + l16) * 32 + quad * 8);

    const int hq = (nqw >> 4) & 15;
    const int dq = nq0 >> 8;
    float dw2[4];
    #pragma unroll
    for (int r = 0; r < 4; ++r) {
        const float dw = (float)(quad * 4 + r - l16);
        dw2[r] = dw * dw;
    }

    const int dk_lo = (dq > 9) ? dq - 9 : 0;
    const int dk_hi = (dq < 6) ? dq + 9 : 15;
    const int NT = 4 * (dk_hi - dk_lo + 1);   // 40..64, even

    // K staging roles (256 threads move one 4KB K-tile per slot)
    const int skey = tid >> 2;
    const int sdo  = (tid & 3) * 8;
    const unsigned short* ksrc = km + ((size_t)h << 17) + skey * 32 + sdo;
    const int kdst = (skey * 32 + sdo) ^ ((skey & 7) << 3);

    // per-wave direct V pointers (R15 pattern): A[m=dim l16][k=key quad*8+j]
    const unsigned short* vt0 = vt + (((size_t)h * 32 + l16) << 12) + quad * 8;
    const unsigned short* vt1 = vt0 + (16 << 12);

    float l_acc = 0.f;
    floatx4 o_acc[2][2] = {};                 // [slot][hf]

#define J0T(T) (((dk_lo + ((T) >> 2)) << 8) + (((T) & 3) << 6))

    short8 rK[2];
#define LOAD2(TA, TB) {                                                   \
        const int ja_ = J0T(TA), jb_ = J0T(TB);                           \
        rK[0] = *reinterpret_cast<const short8*>(ksrc + (size_t)ja_ * 32);\
        rK[1] = *reinterpret_cast<const short8*>(ksrc + (size_t)jb_ * 32);\
    }
#define WRITE2(NB) {                                                      \
        *reinterpret_cast<short8*>(&Kt[NB][0][kdst]) = rK[0];             \
        *reinterpret_cast<short8*>(&Kt[NB][1][kdst]) = rK[1];             \
    }

// branch-free S stage: every subtile computes; dead ones give exact P=0 (cndmask)
#define SSTAGE(T, CB, SL) {                                               \
        const int dk_ = dk_lo + ((T) >> 2), g_ = (T) & 3;                 \
        const int dd_ = dq - dk_;                                         \
        const int bb_ = 100 - dd_ * dd_;                                  \
        const int h0_ = hq - 4 * g_;                                      \
        int th_[4];                                                       \
        th_[0] = bb_ - h0_ * h0_;                                         \
        th_[1] = bb_ - (h0_ - 1) * (h0_ - 1);                             \
        th_[2] = bb_ - (h0_ - 2) * (h0_ - 2);                             \
        th_[3] = bb_ - (h0_ - 3) * (h0_ - 3);                             \
        _Pragma("unroll")                                                 \
        for (int t4 = 0; t4 < 4; ++t4) {                                  \
            const short8 kf = *reinterpret_cast<const short8*>(           \
                &Kt[CB][SL][((t4 * 16 + l16) * 32 + quad * 8) ^ ((l16 & 7) << 3)]); \
            const floatx4 sf = __builtin_amdgcn_mfma_f32_16x16x32_bf16(   \
                kf, a_q, (floatx4){0.f, 0.f, 0.f, 0.f}, 0, 0, 0);         \
            const float thrf = (float)th_[t4];                            \
            const float p0 = (dw2[0] < thrf) ? EXP2(sf[0]) : 0.f;         \
            const float p1 = (dw2[1] < thrf) ? EXP2(sf[1]) : 0.f;         \
            const float p2 = (dw2[2] < thrf) ? EXP2(sf[2]) : 0.f;         \
            const float p3 = (dw2[3] < thrf) ? EXP2(sf[3]) : 0.f;         \
            l_acc += (p0 + p1) + (p2 + p3);                               \
            unsigned int pair_[2];                                        \
            pair_[0] = pk_bf16(p0, p1);                                   \
            pair_[1] = pk_bf16(p2, p3);                                   \
            __builtin_memcpy(&PT[wv][SL][l16][t4 * 16 + quad * 4], pair_, 8); \
        }                                                                 \
    }

// PV from PT[SL] with V fragments in registers (V00..V11 = kt/hf pairs)
#define PVST(SL, V00, V01, V10, V11) {                                    \
        _Pragma("unroll")                                                 \
        for (int kt = 0; kt < 2; ++kt) {                                  \
            const short8 b_p = *reinterpret_cast<const short8*>(          \
                &PT[wv][SL][l16][kt * 32 + quad * 8]);                    \
            o_acc[SL][0] = __builtin_amdgcn_mfma_f32_16x16x32_bf16(       \
                kt ? V10 : V00, b_p, o_acc[SL][0], 0, 0, 0);              \
            o_acc[SL][1] = __builtin_amdgcn_mfma_f32_16x16x32_bf16(       \
                kt ? V11 : V01, b_p, o_acc[SL][1], 0, 0, 0);              \
        }                                                                 \
    }

    // prologue: K tiles 0,1 -> buf0; K tiles 2,3 -> regs
    LOAD2(0, 1)
    WRITE2(0)
    LOAD2(2, 3)
    __syncthreads();

    for (int t2 = 0; t2 < NT; t2 += 2) {
        const int cb = (t2 >> 1) & 1, nb = cb ^ 1;

        // V loads for THIS phase's tiles -- issued first, consumed after 2 SSTAGEs
        const int ja = J0T(t2), jb = J0T(t2 + 1);
        const short8 va00 = *reinterpret_cast<const short8*>(vt0 + ja);
        const short8 va01 = *reinterpret_cast<const short8*>(vt1 + ja);
        const short8 va10 = *reinterpret_cast<const short8*>(vt0 + ja + 32);
        const short8 va11 = *reinterpret_cast<const short8*>(vt1 + ja + 32);
        const short8 vb00 = *reinterpret_cast<const short8*>(vt0 + jb);
        const short8 vb01 = *reinterpret_cast<const short8*>(vt1 + jb);
        const short8 vb10 = *reinterpret_cast<const short8*>(vt0 + jb + 32);
        const short8 vb11 = *reinterpret_cast<const short8*>(vt1 + jb + 32);

        WRITE2(nb)                      // K tiles t2+2, t2+3 (vmcnt waits here)
        {
            int ta = t2 + 4; if (ta >= NT) ta = NT - 1;
            int tb = t2 + 5; if (tb >= NT) tb = NT - 1;
            LOAD2(ta, tb)               // issue early; consumed next phase
        }
        SSTAGE(t2,     cb, 0)           // straight-line: two independent chains
        SSTAGE(t2 + 1, cb, 1)
        PVST(0, va00, va01, va10, va11)
        PVST(1, vb00, vb01, vb10, vb11)
        __syncthreads();
    }
#undef PVST
#undef SSTAGE
#undef WRITE2
#undef LOAD2
#undef J0T

    // epilogue: waves own disjoint q-rows; direct write
    l_acc += __shfl_xor(l_acc, 16);
    l_acc += __shfl_xor(l_acc, 32);
    const float inv = RCP(l_acc);
    #pragma unroll
    for (int hf = 0; hf < 2; ++hf) {
        const floatx4 os = o_acc[0][hf] + o_acc[1][hf];
        unsigned int uu[2];
        uu[0] = pk_bf16(os[0] * inv, os[1] * inv);
        uu[1] = pk_bf16(os[2] * inv, os[3] * inv);
        __builtin_memcpy(ao + (size_t)(nqw + l16) * 256 + h * 32 + hf * 16 + quad * 4,
                         uu, 8);
    }
}

// ---------------- 3) proj GEMM + bias (R25 verbatim: 32-wide n-tiles, 2 blocks/CU) ----------------
__global__ __launch_bounds__(256) void k_proj(const unsigned short* __restrict__ ao,
                                              const float* __restrict__ pw,
                                              const float* __restrict__ pb,
                                              float* __restrict__ out) {
    __shared__ __align__(16) unsigned short Pt[64][264];
    const int tid = threadIdx.x;
    const int wave = tid >> 6, lane = tid & 63;
    const int l16 = lane & 15, quad = lane >> 4;
    const int n0 = blockIdx.x * 32;
    const int m0 = blockIdx.y * 64;

    {
        const int o_l = tid >> 2, cp = (tid & 3) * 64;
        const float4* wp = reinterpret_cast<const float4*>(pw + (size_t)(m0 + o_l) * 256 + cp);
        #pragma unroll
        for (int j = 0; j < 4; ++j) {
            const float4 g0 = wp[4 * j + 0], g1 = wp[4 * j + 1];
            const float4 g2 = wp[4 * j + 2], g3 = wp[4 * j + 3];
            unsigned int u[8];
            u[0] = pk_bf16(g0.x, g0.y); u[1] = pk_bf16(g0.z, g0.w);
            u[2] = pk_bf16(g1.x, g1.y); u[3] = pk_bf16(g1.z, g1.w);
            u[4] = pk_bf16(g2.x, g2.y); u[5] = pk_bf16(g2.z, g2.w);
            u[6] = pk_bf16(g3.x, g3.y); u[7] = pk_bf16(g3.z, g3.w);
            __builtin_memcpy(&Pt[o_l][cp + 16 * j], u, 32);
        }
    }
    __syncthreads();

    floatx4 acc[2] = {};
    #pragma unroll
    for (int cc = 0; cc < 8; ++cc) {
        const int c0 = cc * 32 + quad * 8;
        const short8 a = *reinterpret_cast<const short8*>(&Pt[wave * 16 + l16][c0]);
        #pragma unroll
        for (int t4 = 0; t4 < 2; ++t4) {
            const short8 b = *reinterpret_cast<const short8*>(
                ao + (size_t)(n0 + t4 * 16 + l16) * 256 + c0);
            acc[t4] = __builtin_amdgcn_mfma_f32_16x16x32_bf16(a, b, acc[t4], 0, 0, 0);
        }
    }
    #pragma unroll
    for (int t4 = 0; t4 < 2; ++t4) {
        #pragma unroll
        for (int r = 0; r < 4; ++r) {
            const int o = m0 + wave * 16 + quad * 4 + r;
            const int n = n0 + t4 * 16 + l16;
            out[(size_t)o * 4096 + n] = acc[t4][r] + pb[o];
        }
    }
}

extern "C" void kernel_launch(void* const* d_in, const int* in_sizes, int n_in,
                              void* d_out, int out_size, void* d_ws, size_t ws_size,
                              hipStream_t stream) {
    const float* x      = (const float*)d_in[0];
    const float* qkv_w  = (const float*)d_in[1];
    const float* proj_w = (const float*)d_in[2];
    const float* proj_b = (const float*)d_in[3];
    float* out = (float*)d_out;                    // [256,4096] fp32

    char* B = (char*)d_ws;
    const size_t MB = 1u << 20;
    unsigned short* ao = (unsigned short*)(B);
    unsigned short* qm = (unsigned short*)(B + 2 * MB);
    unsigned short* km = (unsigned short*)(B + 4 * MB);
    unsigned short* vt = (unsigned short*)(B + 6 * MB);

    k_qkv<<<dim3(64, 12), 256, 0, stream>>>(x, qkv_w, qm, km, vt);
    k_attn<<<dim3(64, 8), 256, 0, stream>>>(qm, km, vt, ao);
    k_proj<<<dim3(128, 4), 256, 0, stream>>>(ao, proj_w, proj_b, out);
}

// Round 16
// 134.656 us; speedup vs baseline: 1.0864x; 1.0864x over previous
//
#include <hip/hip_runtime.h>
#include <hip/hip_bf16.h>

typedef __attribute__((ext_vector_type(8))) short short8;
typedef __attribute__((ext_vector_type(4))) float floatx4;

#define L2E 1.4426950408889634f

#if __has_builtin(__builtin_amdgcn_exp2f)
#define EXP2(x) __builtin_amdgcn_exp2f(x)
#else
#define EXP2(x) exp2f(x)
#endif
#if __has_builtin(__builtin_amdgcn_rcpf)
#define RCP(x) __builtin_amdgcn_rcpf(x)
#else
#define RCP(x) (1.0f / (x))
#endif

static __device__ __forceinline__ unsigned short f2bf(float f) {
    unsigned int u = __builtin_bit_cast(unsigned int, f);
    u += 0x7fffu + ((u >> 16) & 1u);   // RNE
    return (unsigned short)(u >> 16);
}
static __device__ __forceinline__ unsigned int pk_bf16(float a, float b) {
    __hip_bfloat162 h2 = __float22bfloat162_rn(make_float2(a, b));   // v_cvt_pk_bf16_f32
    unsigned int u;
    __builtin_memcpy(&u, &h2, 4);     // low16 = a, high16 = b
    return u;
}

// ---------------- 1) QKV GEMM (R25 verbatim: vectorized staging, LDS-bounced V^T) ----------------
__global__ __launch_bounds__(256) void k_qkv(const float* __restrict__ x,
                                             const float* __restrict__ qw,
                                             unsigned short* __restrict__ qm,
                                             unsigned short* __restrict__ km,
                                             unsigned short* __restrict__ vt) {
    __shared__ __align__(16) unsigned short At[64][136];
    __shared__ __align__(16) unsigned short Wt[64][136];
    const int tid = threadIdx.x;
    const int wave = tid >> 6, lane = tid & 63;
    const int l16 = lane & 15, quad = lane >> 4;
    const int m0 = blockIdx.x * 64;
    const int o0 = blockIdx.y * 64;

    floatx4 acc[4] = {};
    for (int rnd = 0; rnd < 2; ++rnd) {
        const int cbase = rnd * 128;
        if (rnd) __syncthreads();
        {
            const int tok0 = (tid & 15) * 4;
            const int c0   = (tid >> 4) * 8;
            const float* xp = x + (size_t)(cbase + c0) * 4096 + m0 + tok0;
            float4 v[8];
            #pragma unroll
            for (int j = 0; j < 8; ++j)
                v[j] = *reinterpret_cast<const float4*>(xp + (size_t)j * 4096);
            #pragma unroll
            for (int t = 0; t < 4; ++t) {
                unsigned int d[4];
                d[0] = pk_bf16((&v[0].x)[t], (&v[1].x)[t]);
                d[1] = pk_bf16((&v[2].x)[t], (&v[3].x)[t]);
                d[2] = pk_bf16((&v[4].x)[t], (&v[5].x)[t]);
                d[3] = pk_bf16((&v[6].x)[t], (&v[7].x)[t]);
                __builtin_memcpy(&At[tok0 + t][c0], d, 16);
            }
        }
        {
            const int o_l = tid >> 2, cp = (tid & 3) * 32;
            const float4* wp = reinterpret_cast<const float4*>(
                qw + (size_t)(o0 + o_l) * 256 + cbase + cp);
            #pragma unroll
            for (int j = 0; j < 2; ++j) {
                const float4 g0 = wp[4 * j + 0], g1 = wp[4 * j + 1];
                const float4 g2 = wp[4 * j + 2], g3 = wp[4 * j + 3];
                unsigned int u[8];
                u[0] = pk_bf16(g0.x, g0.y); u[1] = pk_bf16(g0.z, g0.w);
                u[2] = pk_bf16(g1.x, g1.y); u[3] = pk_bf16(g1.z, g1.w);
                u[4] = pk_bf16(g2.x, g2.y); u[5] = pk_bf16(g2.z, g2.w);
                u[6] = pk_bf16(g3.x, g3.y); u[7] = pk_bf16(g3.z, g3.w);
                __builtin_memcpy(&Wt[o_l][cp + 16 * j], u, 32);
            }
        }
        __syncthreads();
        #pragma unroll
        for (int cc = 0; cc < 4; ++cc) {
            const int c0 = cc * 32 + quad * 8;
            const short8 a = *reinterpret_cast<const short8*>(&At[wave * 16 + l16][c0]);
            #pragma unroll
            for (int t4 = 0; t4 < 4; ++t4) {
                const short8 b = *reinterpret_cast<const short8*>(&Wt[t4 * 16 + l16][c0]);
                acc[t4] = __builtin_amdgcn_mfma_f32_16x16x32_bf16(a, b, acc[t4], 0, 0, 0);
            }
        }
    }

    const int s = o0 >> 8;   // block-uniform: 0=q, 1=k, 2=v
    if (s < 2) {
        const float qscale = 0.17677669529663687f * L2E;
        #pragma unroll
        for (int t4 = 0; t4 < 4; ++t4) {
            #pragma unroll
            for (int r = 0; r < 4; ++r) {
                const int n = m0 + wave * 16 + quad * 4 + r;
                const int o = o0 + t4 * 16 + l16;
                const int rem = o & 255, head = rem >> 5, t = rem & 31;
                if (s == 0)  qm[((size_t)head * 4096 + n) * 32 + t] = f2bf(acc[t4][r] * qscale);
                else         km[((size_t)head * 4096 + n) * 32 + t] = f2bf(acc[t4][r]);
            }
        }
    } else {
        __syncthreads();
        unsigned short (*Ct)[72] = reinterpret_cast<unsigned short(*)[72]>(&At[0][0]);
        #pragma unroll
        for (int t4 = 0; t4 < 4; ++t4) {
            unsigned int d2[2];
            d2[0] = pk_bf16(acc[t4][0], acc[t4][1]);
            d2[1] = pk_bf16(acc[t4][2], acc[t4][3]);
            __builtin_memcpy(&Ct[t4 * 16 + l16][wave * 16 + quad * 4], d2, 8);
        }
        __syncthreads();
        const int row = tid >> 2, col0 = (tid & 3) * 16;
        unsigned short* dst = vt + (size_t)(o0 - 512 + row) * 4096 + m0 + col0;
        const short8 ca = *reinterpret_cast<const short8*>(&Ct[row][col0]);
        const short8 cb = *reinterpret_cast<const short8*>(&Ct[row][col0 + 8]);
        *reinterpret_cast<short8*>(dst) = ca;
        *reinterpret_cast<short8*>(dst + 8) = cb;
    }
}

// ---------------- 2) flash attention: R28 (2 branch-free chains/phase) + T5 setprio ----------------
// R31 == R30 resubmitted (R30 bench was an infra failure, no data). Single diff
// vs the passing R28 (61.0us attn): s_setprio(1) around the compute section,
// prio 0 through staging/barrier. The two co-resident blocks per CU are NOT
// barrier-synced -> real role diversity per SIMD; setprio lets compute-phase
// waves win issue arbitration (T5, m191: attn +4-7%). setprio is a scalar hint
// with no memory/exec semantics -- cannot affect correctness.
__global__ __launch_bounds__(256, 2) void k_attn(const unsigned short* __restrict__ qm,
                                                 const unsigned short* __restrict__ km,
                                                 const unsigned short* __restrict__ vt,
                                                 unsigned short* __restrict__ ao) {
    const int h   = blockIdx.y;
    const int nq0 = blockIdx.x * 64;          // 64 q-rows per block (same dq for all)
    const int tid = threadIdx.x;
    const int wv  = tid >> 6;                 // wave owns q-tile nq0 + wv*16
    const int lane = tid & 63;
    const int l16 = lane & 15, quad = lane >> 4;
    const int nqw = nq0 + wv * 16;

    __shared__ __align__(16) unsigned short Kt[2][2][2048];   // [buf][slot][key*32+dim ^ swz]
    __shared__ __align__(16) unsigned short Vt[2][2][2048];   // [buf][slot][kg*256+dim*8 ^ swz]
    __shared__ __align__(16) unsigned short PT[4][2][16][72]; // [wave][slot][q][key] plain

    const short8 a_q = *reinterpret_cast<const short8*>(
        qm + ((size_t)h * 4096 + nqw + l16) * 32 + quad * 8);

    const int hq = (nqw >> 4) & 15;
    const int dq = nq0 >> 8;
    float dw2[4];
    #pragma unroll
    for (int r = 0; r < 4; ++r) {
        const float dw = (float)(quad * 4 + r - l16);
        dw2[r] = dw * dw;
    }

    const int dk_lo = (dq > 9) ? dq - 9 : 0;
    const int dk_hi = (dq < 6) ? dq + 9 : 15;
    const int NT = 4 * (dk_hi - dk_lo + 1);   // 40..64, even

    const int skey = tid >> 2;
    const int sdo  = (tid & 3) * 8;
    const int sdim = tid >> 3;
    const int skg  = tid & 7;
    const unsigned short* ksrc = km + ((size_t)h << 17) + skey * 32 + sdo;
    const unsigned short* vsrc = vt + (((size_t)h * 32 + sdim) << 12) + skg * 8;
    const int kdst = (skey * 32 + sdo) ^ ((skey & 7) << 3);
    const int vdst = (skg * 256 + sdim * 8) ^ (skg << 3);

    float l_acc = 0.f;
    floatx4 o_acc[2][2] = {};                 // [slot][hf]

#define J0T(T) (((dk_lo + ((T) >> 2)) << 8) + (((T) & 3) << 6))

    short8 rK[2], rV[2];
#define LOAD2(TA, TB) {                                                   \
        const int ja_ = J0T(TA), jb_ = J0T(TB);                           \
        rK[0] = *reinterpret_cast<const short8*>(ksrc + (size_t)ja_ * 32);\
        rV[0] = *reinterpret_cast<const short8*>(vsrc + ja_);             \
        rK[1] = *reinterpret_cast<const short8*>(ksrc + (size_t)jb_ * 32);\
        rV[1] = *reinterpret_cast<const short8*>(vsrc + jb_);             \
    }
#define WRITE2(NB) {                                                      \
        *reinterpret_cast<short8*>(&Kt[NB][0][kdst]) = rK[0];             \
        *reinterpret_cast<short8*>(&Vt[NB][0][vdst]) = rV[0];             \
        *reinterpret_cast<short8*>(&Kt[NB][1][kdst]) = rK[1];             \
        *reinterpret_cast<short8*>(&Vt[NB][1][vdst]) = rV[1];             \
    }

// branch-free S stage: every subtile computes; dead ones give exact P=0 (cndmask)
#define SSTAGE(T, CB, SL) {                                               \
        const int dk_ = dk_lo + ((T) >> 2), g_ = (T) & 3;                 \
        const int dd_ = dq - dk_;                                         \
        const int bb_ = 100 - dd_ * dd_;                                  \
        const int h0_ = hq - 4 * g_;                                      \
        int th_[4];                                                       \
        th_[0] = bb_ - h0_ * h0_;                                         \
        th_[1] = bb_ - (h0_ - 1) * (h0_ - 1);                             \
        th_[2] = bb_ - (h0_ - 2) * (h0_ - 2);                             \
        th_[3] = bb_ - (h0_ - 3) * (h0_ - 3);                             \
        _Pragma("unroll")                                                 \
        for (int t4 = 0; t4 < 4; ++t4) {                                  \
            const short8 kf = *reinterpret_cast<const short8*>(           \
                &Kt[CB][SL][((t4 * 16 + l16) * 32 + quad * 8) ^ ((l16 & 7) << 3)]); \
            const floatx4 sf = __builtin_amdgcn_mfma_f32_16x16x32_bf16(   \
                kf, a_q, (floatx4){0.f, 0.f, 0.f, 0.f}, 0, 0, 0);         \
            const float thrf = (float)th_[t4];                            \
            const float p0 = (dw2[0] < thrf) ? EXP2(sf[0]) : 0.f;         \
            const float p1 = (dw2[1] < thrf) ? EXP2(sf[1]) : 0.f;         \
            const float p2 = (dw2[2] < thrf) ? EXP2(sf[2]) : 0.f;         \
            const float p3 = (dw2[3] < thrf) ? EXP2(sf[3]) : 0.f;         \
            l_acc += (p0 + p1) + (p2 + p3);                               \
            unsigned int pair_[2];                                        \
            pair_[0] = pk_bf16(p0, p1);                                   \
            pair_[1] = pk_bf16(p2, p3);                                   \
            __builtin_memcpy(&PT[wv][SL][l16][t4 * 16 + quad * 4], pair_, 8); \
        }                                                                 \
    }

#define PVST(CB, SL) {                                                    \
        _Pragma("unroll")                                                 \
        for (int kt = 0; kt < 2; ++kt) {                                  \
            const short8 b_p = *reinterpret_cast<const short8*>(          \
                &PT[wv][SL][l16][kt * 32 + quad * 8]);                    \
            const int kg = kt * 4 + quad;                                 \
            _Pragma("unroll")                                             \
            for (int hf = 0; hf < 2; ++hf) {                              \
                const short8 vf = *reinterpret_cast<const short8*>(       \
                    &Vt[CB][SL][(kg * 256 + (hf * 16 + l16) * 8) ^ (kg << 3)]); \
                o_acc[SL][hf] = __builtin_amdgcn_mfma_f32_16x16x32_bf16(  \
                    vf, b_p, o_acc[SL][hf], 0, 0, 0);                     \
            }                                                             \
        }                                                                 \
    }

    // prologue: tiles 0,1 -> buf0; tiles 2,3 -> regs
    LOAD2(0, 1)
    WRITE2(0)
    LOAD2(2, 3)
    __syncthreads();

    for (int t2 = 0; t2 < NT; t2 += 2) {
        const int cb = (t2 >> 1) & 1, nb = cb ^ 1;
        WRITE2(nb)                      // tiles t2+2, t2+3 (vmcnt waits here)
        {
            int ta = t2 + 4; if (ta >= NT) ta = NT - 1;
            int tb = t2 + 5; if (tb >= NT) tb = NT - 1;
            LOAD2(ta, tb)               // issue early; consumed next phase
        }
        __builtin_amdgcn_s_setprio(1);  // T5: compute section wins SIMD arbitration
        SSTAGE(t2,     cb, 0)           // straight-line: two independent chains
        SSTAGE(t2 + 1, cb, 1)
        PVST(cb, 0)
        PVST(cb, 1)
        __builtin_amdgcn_s_setprio(0);
        __syncthreads();
    }
#undef PVST
#undef SSTAGE
#undef WRITE2
#undef LOAD2
#undef J0T

    // epilogue: waves own disjoint q-rows; direct write
    l_acc += __shfl_xor(l_acc, 16);
    l_acc += __shfl_xor(l_acc, 32);
    const float inv = RCP(l_acc);
    #pragma unroll
    for (int hf = 0; hf < 2; ++hf) {
        const floatx4 os = o_acc[0][hf] + o_acc[1][hf];
        unsigned int uu[2];
        uu[0] = pk_bf16(os[0] * inv, os[1] * inv);
        uu[1] = pk_bf16(os[2] * inv, os[3] * inv);
        __builtin_memcpy(ao + (size_t)(nqw + l16) * 256 + h * 32 + hf * 16 + quad * 4,
                         uu, 8);
    }
}

// ---------------- 3) proj GEMM + bias (R25 verbatim: 32-wide n-tiles, 2 blocks/CU) ----------------
__global__ __launch_bounds__(256) void k_proj(const unsigned short* __restrict__ ao,
                                              const float* __restrict__ pw,
                                              const float* __restrict__ pb,
                                              float* __restrict__ out) {
    __shared__ __align__(16) unsigned short Pt[64][264];
    const int tid = threadIdx.x;
    const int wave = tid >> 6, lane = tid & 63;
    const int l16 = lane & 15, quad = lane >> 4;
    const int n0 = blockIdx.x * 32;
    const int m0 = blockIdx.y * 64;

    {
        const int o_l = tid >> 2, cp = (tid & 3) * 64;
        const float4* wp = reinterpret_cast<const float4*>(pw + (size_t)(m0 + o_l) * 256 + cp);
        #pragma unroll
        for (int j = 0; j < 4; ++j) {
            const float4 g0 = wp[4 * j + 0], g1 = wp[4 * j + 1];
            const float4 g2 = wp[4 * j + 2], g3 = wp[4 * j + 3];
            unsigned int u[8];
            u[0] = pk_bf16(g0.x, g0.y); u[1] = pk_bf16(g0.z, g0.w);
            u[2] = pk_bf16(g1.x, g1.y); u[3] = pk_bf16(g1.z, g1.w);
            u[4] = pk_bf16(g2.x, g2.y); u[5] = pk_bf16(g2.z, g2.w);
            u[6] = pk_bf16(g3.x, g3.y); u[7] = pk_bf16(g3.z, g3.w);
            __builtin_memcpy(&Pt[o_l][cp + 16 * j], u, 32);
        }
    }
    __syncthreads();

    floatx4 acc[2] = {};
    #pragma unroll
    for (int cc = 0; cc < 8; ++cc) {
        const int c0 = cc * 32 + quad * 8;
        const short8 a = *reinterpret_cast<const short8*>(&Pt[wave * 16 + l16][c0]);
        #pragma unroll
        for (int t4 = 0; t4 < 2; ++t4) {
            const short8 b = *reinterpret_cast<const short8*>(
                ao + (size_t)(n0 + t4 * 16 + l16) * 256 + c0);
            acc[t4] = __builtin_amdgcn_mfma_f32_16x16x32_bf16(a, b, acc[t4], 0, 0, 0);
        }
    }
    #pragma unroll
    for (int t4 = 0; t4 < 2; ++t4) {
        #pragma unroll
        for (int r = 0; r < 4; ++r) {
            const int o = m0 + wave * 16 + quad * 4 + r;
            const int n = n0 + t4 * 16 + l16;
            out[(size_t)o * 4096 + n] = acc[t4][r] + pb[o];
        }
    }
}

extern "C" void kernel_launch(void* const* d_in, const int* in_sizes, int n_in,
                              void* d_out, int out_size, void* d_ws, size_t ws_size,
                              hipStream_t stream) {
    const float* x      = (const float*)d_in[0];
    const float* qkv_w  = (const float*)d_in[1];
    const float* proj_w = (const float*)d_in[2];
    const float* proj_b = (const float*)d_in[3];
    float* out = (float*)d_out;                    // [256,4096] fp32

    char* B = (char*)d_ws;
    const size_t MB = 1u << 20;
    unsigned short* ao = (unsigned short*)(B);
    unsigned short* qm = (unsigned short*)(B + 2 * MB);
    unsigned short* km = (unsigned short*)(B + 4 * MB);
    unsigned short* vt = (unsigned short*)(B + 6 * MB);

    k_qkv<<<dim3(64, 12), 256, 0, stream>>>(x, qkv_w, qm, km, vt);
    k_attn<<<dim3(64, 8), 256, 0, stream>>>(qm, km, vt, ao);
    k_proj<<<dim3(128, 4), 256, 0, stream>>>(ao, proj_w, proj_b, out);
}